// Round 3
// baseline (158.465 us; speedup 1.0000x reference)
//
#include <hip/hip_runtime.h>
#include <hip/hip_bf16.h>
#include <cstdint>

typedef __bf16 bf16;
typedef __bf16 bf16x4 __attribute__((ext_vector_type(4)));
typedef __bf16 bf16x8 __attribute__((ext_vector_type(8)));
typedef float floatx4 __attribute__((ext_vector_type(4)));

typedef __attribute__((address_space(1))) void as1_void;
typedef __attribute__((address_space(3))) void as3_void;

// async global->LDS, 16B per lane. LDS dest must be wave-uniform base + lane*16.
__device__ __forceinline__ void gld16(const void* g, void* l) {
#if __has_builtin(__builtin_amdgcn_global_load_lds)
  __builtin_amdgcn_global_load_lds((as1_void*)(uintptr_t)g, (as3_void*)l, 16, 0, 0);
#else
  *(uint4*)l = *(const uint4*)g;
#endif
}

// ---------------- fp32 -> bf16 conversion (x, Wq|Wk|Wv concat, Wo) -------------
__global__ __launch_bounds__(256) void convert_kernel(
    const float* __restrict__ x, const float* __restrict__ wq,
    const float* __restrict__ wk, const float* __restrict__ wv,
    const float* __restrict__ wo, bf16* __restrict__ xbf,
    bf16* __restrict__ wqkv, bf16* __restrict__ wob) {
  int i = blockIdx.x * 256 + threadIdx.x;  // one float4 (4 elems) per thread
  const float* src;
  bf16* dst;
  int off;
  if (i < 1048576) {            // x: 4,194,304 elems
    src = x; dst = xbf; off = i;
  } else if (i < 1310720) {     // Wq
    src = wq; dst = wqkv; off = i - 1048576;
  } else if (i < 1572864) {     // Wk
    src = wk; dst = wqkv + 1048576; off = i - 1310720;
  } else if (i < 1835008) {     // Wv
    src = wv; dst = wqkv + 2097152; off = i - 1572864;
  } else {                      // Wo
    src = wo; dst = wob; off = i - 1835008;
  }
  float4 v = ((const float4*)src)[off];
  bf16x4 o;
  o[0] = (bf16)v.x; o[1] = (bf16)v.y; o[2] = (bf16)v.z; o[3] = (bf16)v.w;
  ((bf16x4*)dst)[off] = o;
}

// ---------------- NT GEMM: C[M,N] = A[M,K] @ B[N,K]^T --------------------------
// 128 x BN tile, BK=64 (two stride-32 slabs), 256 threads = 2x2 waves.
// LDS slab layout keeps the known-good stride-32 contiguous frag reads AND the
// gld16 dest = base + chunk*16 contiguity (chunk c -> elem offset c*8).
// Split-K via gridDim.z: MODE 0 (bf16 out) requires gridDim.z==1;
// MODE 1 writes fp32 partials at Cf + z*M*N (bias applied by reduce kernel).
template <int MODE, int BN>
__global__ __launch_bounds__(256) void gemm_nt(const bf16* __restrict__ A,
                                               const bf16* __restrict__ Bm,
                                               bf16* __restrict__ Cb,
                                               float* __restrict__ Cf,
                                               int M, int N, int K) {
  constexpr int WN = BN / 2;       // wave n-extent
  constexpr int NI = WN / 16;      // n-tiles per wave
  __shared__ __attribute__((aligned(16))) bf16 As[2 * 128 * 32];
  __shared__ __attribute__((aligned(16))) bf16 Bs[2 * BN * 32];
  const int tid = threadIdx.x;
  const int lane = tid & 63;
  const int wave = tid >> 6;
  const int quad = lane >> 4;
  const int n0 = lane & 15;
  const int wm = wave >> 1;
  const int wn = wave & 1;
  const int bN = blockIdx.x, bM = blockIdx.y, bZ = blockIdx.z;
  const int Kslice = K / gridDim.z;
  const int kBeg = bZ * Kslice;
  const bf16* Ab = A + (size_t)bM * 128 * K;
  const bf16* Bb = Bm + (size_t)bN * BN * K;
  floatx4 acc[4][NI] = {};
  for (int k0 = kBeg; k0 < kBeg + Kslice; k0 += 64) {
    // A: 1024 chunks (slab|row|kq), 4 per thread; LDS elem offset = c*8
#pragma unroll
    for (int it = 0; it < 4; ++it) {
      const int c = it * 256 + tid;
      const int slab = c >> 9, rk = c & 511, row = rk >> 2, kq = rk & 3;
      gld16(Ab + (size_t)row * K + k0 + slab * 32 + kq * 8, &As[c * 8]);
    }
    // B: BN*8 chunks
#pragma unroll
    for (int cc = 0; cc < BN * 8; cc += 256) {
      const int c = cc + tid;
      const int slab = c / (BN * 4), rk = c % (BN * 4), row = rk >> 2, kq = rk & 3;
      gld16(Bb + (size_t)row * K + k0 + slab * 32 + kq * 8, &Bs[c * 8]);
    }
    __syncthreads();
#pragma unroll
    for (int ks = 0; ks < 2; ++ks) {
      bf16x8 af[4], bfr[NI];
#pragma unroll
      for (int mi = 0; mi < 4; ++mi)
        af[mi] = *(const bf16x8*)&As[ks * 4096 + (wm * 64 + mi * 16 + n0) * 32 + quad * 8];
#pragma unroll
      for (int ni = 0; ni < NI; ++ni)
        bfr[ni] = *(const bf16x8*)&Bs[ks * BN * 32 + (wn * WN + ni * 16 + n0) * 32 + quad * 8];
#pragma unroll
      for (int mi = 0; mi < 4; ++mi)
#pragma unroll
        for (int ni = 0; ni < NI; ++ni)
          acc[mi][ni] = __builtin_amdgcn_mfma_f32_16x16x32_bf16(
              af[mi], bfr[ni], acc[mi][ni], 0, 0, 0);
    }
    __syncthreads();
  }
  const int rowBase = bM * 128 + wm * 64;
  const int colBase = bN * BN + wn * WN;
  float* Cfp = Cf + (size_t)bZ * M * N;
#pragma unroll
  for (int ni = 0; ni < NI; ++ni) {
    const int col = colBase + ni * 16 + n0;
#pragma unroll
    for (int mi = 0; mi < 4; ++mi)
#pragma unroll
      for (int r = 0; r < 4; ++r) {
        const int row = rowBase + mi * 16 + quad * 4 + r;
        if (MODE == 0)
          Cb[(size_t)row * N + col] = (bf16)acc[mi][ni][r];
        else
          Cfp[(size_t)row * N + col] = acc[mi][ni][r];
      }
  }
}

// ---------------- split-K reduce + bias ----------------------------------------
// out[i] = p[0][i] + p[1][i] + bias[i % 1024]; float4 per thread, 4096 blocks.
__global__ __launch_bounds__(256) void reduce_bias_kernel(
    const float* __restrict__ p, const float* __restrict__ bias,
    float* __restrict__ out) {
  const int i = blockIdx.x * 256 + threadIdx.x;  // float4 index, 1,048,576 total
  float4 a = ((const float4*)p)[i];
  float4 c = ((const float4*)(p + 4194304))[i];
  float4 bi = ((const float4*)bias)[i & 255];  // (4i mod 1024)/4
  float4 o;
  o.x = a.x + c.x + bi.x;
  o.y = a.y + c.y + bi.y;
  o.z = a.z + c.z + bi.z;
  o.w = a.w + c.w + bi.w;
  ((float4*)out)[i] = o;
}

// ---------------- sliding-window attention ------------------------------------
// block = (b, h, 64-query tile); 4 waves, wave w owns queries [w*16, w*16+16).
// Key window rows t=0..127 <-> j = i0-32+t; out-of-range rows are zero
// (matches reference zero-padding: score 0 participates in softmax, V adds 0).
// LDS strides chosen so every frag access is <=2 lanes/bank (free, m136).
// Total LDS 54,272 B -> 3 blocks/CU (162,816 <= 163,840).
__global__ __launch_bounds__(256) void attn_kernel(const bf16* __restrict__ qkv,
                                                   bf16* __restrict__ aout) {
  __shared__ __attribute__((aligned(16))) bf16 Ks[128 * 72];
  __shared__ __attribute__((aligned(16))) bf16 VsPs[128 * 72];  // Vs, then Ps
  __shared__ __attribute__((aligned(16))) bf16 Vt[64 * 136];
  const int bid = blockIdx.x;
  const int b = bid >> 9;            // 512 blocks per batch (16 heads x 32 tiles)
  const int h = (bid >> 5) & 15;
  const int i0 = (bid & 31) * 64;
  const int tid = threadIdx.x;
  const int wave = tid >> 6, lane = tid & 63;
  const int quad = lane >> 4, n0 = lane & 15;
  bf16* Vs = VsPs;

  // stage K and V windows: 128 rows x 8 16B-chunks each, zero out-of-range
#pragma unroll
  for (int it = 0; it < 4; ++it) {
    const int idx = it * 256 + tid;
    const int r = idx >> 3, c = idx & 7;
    const int j = i0 - 32 + r;
    uint4 kv_ = make_uint4(0u, 0u, 0u, 0u);
    uint4 vv = make_uint4(0u, 0u, 0u, 0u);
    if (j >= 0 && j < 2048) {
      const bf16* base = qkv + (size_t)(b * 2048 + j) * 3072 + 1024 + h * 64 + c * 8;
      kv_ = *(const uint4*)base;
      vv = *(const uint4*)(base + 1024);
    }
    *(uint4*)&Ks[r * 72 + c * 8] = kv_;
    *(uint4*)&Vs[r * 72 + c * 8] = vv;
  }
  __syncthreads();

  // transpose V: Vs[t][d] -> Vt[d][t]  (reads b128, writes 2-lane/bank)
#pragma unroll
  for (int it = 0; it < 4; ++it) {
    const int idx = it * 256 + tid;
    const int t = idx & 127, c = idx >> 7;
    bf16x8 v = *(const bf16x8*)&Vs[t * 72 + c * 8];
#pragma unroll
    for (int jj = 0; jj < 8; ++jj) Vt[(c * 8 + jj) * 136 + t] = v[jj];
  }
  __syncthreads();

  // Q fragments straight from global (each lane's frag is one contiguous 16B)
  bf16x8 aq[2];
#pragma unroll
  for (int ks = 0; ks < 2; ++ks)
    aq[ks] = *(const bf16x8*)(qkv +
        (size_t)(b * 2048 + i0 + wave * 16 + n0) * 3072 + h * 64 + ks * 32 + quad * 8);

  // S = Q(16x64) @ Kwin(128x64)^T : 8 n-tiles x 2 k-steps
  floatx4 accS[8] = {};
#pragma unroll
  for (int nt = 0; nt < 8; ++nt)
#pragma unroll
    for (int ks = 0; ks < 2; ++ks) {
      bf16x8 bk = *(const bf16x8*)&Ks[(nt * 16 + n0) * 72 + ks * 32 + quad * 8];
      accS[nt] = __builtin_amdgcn_mfma_f32_16x16x32_bf16(aq[ks], bk, accS[nt], 0, 0, 0);
    }

  // scale + band mask + softmax (rows live across the 16 lanes of a quad)
  float mrow[4] = {-1e30f, -1e30f, -1e30f, -1e30f};
#pragma unroll
  for (int nt = 0; nt < 8; ++nt)
#pragma unroll
    for (int r = 0; r < 4; ++r) {
      const int q64 = wave * 16 + quad * 4 + r;
      const int t = nt * 16 + n0;
      float s = accS[nt][r] * 0.125f;  // 1/sqrt(64)
      if (t < q64 || t >= q64 + 64) s = -1e30f;
      accS[nt][r] = s;
      mrow[r] = fmaxf(mrow[r], s);
    }
#pragma unroll
  for (int off = 1; off < 16; off <<= 1)
#pragma unroll
    for (int r = 0; r < 4; ++r)
      mrow[r] = fmaxf(mrow[r], __shfl_xor(mrow[r], off));
  float lrow[4] = {0.f, 0.f, 0.f, 0.f};
#pragma unroll
  for (int nt = 0; nt < 8; ++nt)
#pragma unroll
    for (int r = 0; r < 4; ++r) {
      const float e = __expf(accS[nt][r] - mrow[r]);
      accS[nt][r] = e;
      lrow[r] += e;
    }
#pragma unroll
  for (int off = 1; off < 16; off <<= 1)
#pragma unroll
    for (int r = 0; r < 4; ++r) lrow[r] += __shfl_xor(lrow[r], off);

  // P (C-layout) -> LDS A-layout; per-wave region of VsPs (Vs dead after sync2)
  bf16* Pw = &VsPs[wave * 16 * 136];
#pragma unroll
  for (int r = 0; r < 4; ++r) {
    const float inv = 1.f / lrow[r];
#pragma unroll
    for (int nt = 0; nt < 8; ++nt)
      Pw[(quad * 4 + r) * 136 + nt * 16 + n0] = (bf16)(accS[nt][r] * inv);
  }

  // O = P(16x128) @ V(128x64): 4 k-steps x 4 d-tiles, all b128 frag reads
  floatx4 accO[4] = {};
#pragma unroll
  for (int kt = 0; kt < 4; ++kt) {
    bf16x8 ap = *(const bf16x8*)&Pw[n0 * 136 + kt * 32 + quad * 8];
#pragma unroll
    for (int dt = 0; dt < 4; ++dt) {
      bf16x8 bv = *(const bf16x8*)&Vt[(dt * 16 + n0) * 136 + kt * 32 + quad * 8];
      accO[dt] = __builtin_amdgcn_mfma_f32_16x16x32_bf16(ap, bv, accO[dt], 0, 0, 0);
    }
  }
#pragma unroll
  for (int dt = 0; dt < 4; ++dt)
#pragma unroll
    for (int r = 0; r < 4; ++r) {
      const int q64 = wave * 16 + quad * 4 + r;
      aout[(size_t)(b * 2048 + i0 + q64) * 1024 + h * 64 + dt * 16 + n0] =
          (bf16)accO[dt][r];
    }
}

// ---------------- launch -------------------------------------------------------
// ws layout:
//   [0,   8MB) xbf (4096x1024 bf16)   -- reused as attnout after GEMM1
//   [8,  14MB) wqkv bf16 (3072x1024, rows = [Wq;Wk;Wv])
//   [14, 16MB) wob  bf16 (1024x1024)
//   [16, 40MB) qkv  bf16 (4096x3072, row = [Q|K|V])
//   [40, 72MB) fp32 split-K partials for GEMM2 (2 x 4096x1024)
extern "C" void kernel_launch(void* const* d_in, const int* in_sizes, int n_in,
                              void* d_out, int out_size, void* d_ws, size_t ws_size,
                              hipStream_t stream) {
  const float* x = (const float*)d_in[0];
  const float* wq = (const float*)d_in[1];
  const float* wk = (const float*)d_in[2];
  const float* wv = (const float*)d_in[3];
  const float* wo = (const float*)d_in[4];
  const float* bo = (const float*)d_in[5];
  char* ws = (char*)d_ws;
  bf16* xbf = (bf16*)(ws);
  bf16* wqkv = (bf16*)(ws + (8u << 20));
  bf16* wob = (bf16*)(ws + (14u << 20));
  bf16* qkv = (bf16*)(ws + (16u << 20));
  float* part = (float*)(ws + (40u << 20));
  bf16* aout = xbf;  // xbf dead after GEMM1; stream-ordered reuse

  convert_kernel<<<8192, 256, 0, stream>>>(x, wq, wk, wv, wo, xbf, wqkv, wob);
  // QKV projection: (4096 x 3072) = xbf(4096x1024) @ wqkv^T
  gemm_nt<0, 128><<<dim3(24, 32, 1), 256, 0, stream>>>(xbf, wqkv, qkv, nullptr,
                                                       4096, 3072, 1024);
  attn_kernel<<<1024, 256, 0, stream>>>(qkv, aout);
  // output projection, split-K=2: partials = aout @ wob^T
  gemm_nt<1, 128><<<dim3(8, 32, 2), 256, 0, stream>>>(aout, wob, nullptr, part,
                                                      4096, 1024, 1024);
  reduce_bias_kernel<<<4096, 256, 0, stream>>>(part, bo, (float*)d_out);
}